// Round 5
// baseline (9482.344 us; speedup 1.0000x reference)
//
#include <hip/hip_runtime.h>
#include <hip/hip_bf16.h>
#include <hip/hip_cooperative_groups.h>

namespace cg = cooperative_groups;

// ---------------------------------------------------------------------------
// Sophie on MI355X, round 5: persistent cooperative kernel (single-buffer
// LDS, 20.7 KB/block so coop co-residency validation passes) with a
// fallback to per-step dispatches if the cooperative launch is rejected.
// ---------------------------------------------------------------------------

typedef __bf16 bf16x8 __attribute__((ext_vector_type(8)));
typedef float  f32x4  __attribute__((ext_vector_type(4)));

#define NK 1536      // Z cols: k | v | q
#define KD 512

__device__ __forceinline__ void gl_lds16(const void* g, void* l) {
  __builtin_amdgcn_global_load_lds(
      (const __attribute__((address_space(1))) void*)g,
      (__attribute__((address_space(3))) void*)l, 16, 0, 0);
}
__device__ __forceinline__ float sigm(float x) {
  return __builtin_amdgcn_rcpf(1.f + __expf(-x));
}
__device__ __forceinline__ float tanh_f(float x) {
  return 2.f * __builtin_amdgcn_rcpf(1.f + __expf(-2.f * x)) - 1.f;
}
__device__ __forceinline__ float sel4(f32x4 v, int i) {
  float a = (i & 1) ? v[1] : v[0];
  float b = (i & 1) ? v[3] : v[2];
  return (i & 2) ? b : a;
}
__device__ __forceinline__ float pick(int m, float o0, float o1, float o2, float o3) {
  float a = (m & 1) ? o1 : o0;
  float b = (m & 1) ? o3 : o2;
  return (m & 2) ? b : a;
}

struct SP {
  const unsigned short* Wp;
  unsigned short* A0; unsigned short* A1;
  float* Z0; float* Z1;
  float* co; float* ht;            // ht[65][512]
  const float* biasz;
  const float4* bs4; const float4* w04; const float4* w14;
  const float* others; const float* target;
  const float* scene; const float* out_w; const float* out_b;
  float* part; unsigned int* cnt;
  float* out;
};

// ---------------------------------------------------------------------------
// One 128x128 GEMM tile for step p + fused epilogue (LSTM or k/v/q store).
// Single-buffered A-LDS (16 KB), B in registers, same math as R3 (passed).
// ---------------------------------------------------------------------------
__device__ void do_gemm(const SP& P, int p, int id)
{
  __shared__ __align__(16) char aLds[128 * 64 * 2];   // 16 KB

  const int tid = threadIdx.x, wave = tid >> 6, lane = tid & 63;
  const unsigned short* A = (p & 1) ? P.A1 : P.A0;
  __bf16* An = (__bf16*)((p & 1) ? P.A0 : P.A1);
  float* Z = (p & 1) ? P.Z1 : P.Z0;
  const int tin = (p + 1 < 31) ? (p + 1) : 31;
  const int tc  = (p + 1 < 63) ? (p + 1) : 63;
  const float* op = P.others + (size_t)tin * 8192;
  const float* tp = P.target + tc * 2;
  float* htn = P.ht + (size_t)(p + 1) * 512;

  int bm, bn;
  if (id < 528)      { bn = id / 33;              bm = id % 33; }
  else if (id < 784) { int t2 = id - 528; bn = 16 + (t2 >> 5); bm = t2 & 31; }
  else               { bm = 32;                   bn = 24 + (id - 784); }
  const int m0 = bm * 128, n0 = bn * 128;
  const int l15 = lane & 15, lq = lane >> 4;

  int aRow[4], aOff[4], ldsOff[4];
#pragma unroll
  for (int j = 0; j < 4; ++j) {
    int chunk = j * 4 + wave;
    int r = chunk * 8 + (lane >> 3), ch = lane & 7;
    aRow[j]   = m0 + r;
    aOff[j]   = (ch ^ (r & 7)) * 8;
    ldsOff[j] = chunk * 1024;
  }
  const unsigned short* bBase =
      P.Wp + (size_t)((n0 >> 4) + 2 * wave) * 8192 + lq * 128 + l15 * 8;

  f32x4 acc[8][2];
#pragma unroll
  for (int i = 0; i < 8; ++i) { acc[i][0] = f32x4{0,0,0,0}; acc[i][1] = f32x4{0,0,0,0}; }

  bf16x8 bC[2][2], bN[2][2];

#pragma unroll
  for (int j = 0; j < 4; ++j)
    gl_lds16(A + (size_t)aRow[j] * KD + aOff[j], aLds + ldsOff[j]);
#pragma unroll
  for (int c = 0; c < 2; ++c)
#pragma unroll
    for (int nt = 0; nt < 2; ++nt)
      bC[c][nt] = *(const bf16x8*)(bBase + nt * 8192 + c * 512);

  for (int it = 0; it < 8; ++it) {
    __syncthreads();                 // A(it) staged, B(it) in regs
    if (it < 7) {
#pragma unroll
      for (int c = 0; c < 2; ++c)
#pragma unroll
        for (int nt = 0; nt < 2; ++nt)
          bN[c][nt] = *(const bf16x8*)(bBase + nt * 8192 + (it + 1) * 1024 + c * 512);
    }
#pragma unroll
    for (int c = 0; c < 2; ++c) {
      bf16x8 af[8];
#pragma unroll
      for (int mt = 0; mt < 8; ++mt) {
        int row = mt * 16 + l15;
        int ch16 = (c * 4 + lq) ^ (row & 7);
        af[mt] = *(const bf16x8*)(aLds + row * 128 + ch16 * 16);
      }
#pragma unroll
      for (int mt = 0; mt < 8; ++mt)
#pragma unroll
        for (int nt = 0; nt < 2; ++nt)
          acc[mt][nt] = __builtin_amdgcn_mfma_f32_16x16x32_bf16(
              af[mt], bC[c][nt], acc[mt][nt], 0, 0, 0);
    }
    __syncthreads();                 // all waves done reading aLds
    if (it < 7) {
      const int k1 = (it + 1) * 64;
#pragma unroll
      for (int j = 0; j < 4; ++j)
        gl_lds16(A + (size_t)aRow[j] * KD + k1 + aOff[j], aLds + ldsOff[j]);
#pragma unroll
      for (int c = 0; c < 2; ++c)
#pragma unroll
        for (int nt = 0; nt < 2; ++nt) bC[c][nt] = bN[c][nt];
    }
  }

  const int rq = lq * 4;

  if (bn >= 16) {
    // ---- k/v/q epilogue ----
    const int zb = n0 - 2048 + wave * 32;
    float bias[2];
#pragma unroll
    for (int nt = 0; nt < 2; ++nt) bias[nt] = P.biasz[zb + nt * 16 + l15];
#pragma unroll
    for (int mt = 0; mt < 8; ++mt) {
      int rowb = m0 + mt * 16 + rq;
#pragma unroll
      for (int nt = 0; nt < 2; ++nt) {
        int col = zb + nt * 16 + l15;
#pragma unroll
        for (int r = 0; r < 4; ++r)
          Z[(size_t)(rowb + r) * NK + col] = acc[mt][nt][r] + bias[nt];
      }
    }
    return;
  }

  // ---- gate epilogue: fused LSTM cell ----
  const int rho = lane & 3, usel = (lane >> 2) & 3;
  const int u0 = (n0 >> 2) + wave * 8;
  float4 bsv[2], w0v[2], w1v[2];
  int uu[2];
#pragma unroll
  for (int nt = 0; nt < 2; ++nt) {
    uu[nt]  = u0 + nt * 4 + usel;
    bsv[nt] = P.bs4[uu[nt]];
    w0v[nt] = P.w04[uu[nt]];
    w1v[nt] = P.w14[uu[nt]];
  }
#pragma unroll
  for (int mt = 0; mt < 8; ++mt) {
    int row = m0 + mt * 16 + rq + rho;
    bool act = row <= 4096;
    float x0 = 0.f, x1 = 0.f;
    if (act) {
      if (row < 4096) { x0 = op[2 * row]; x1 = op[2 * row + 1]; }
      else            { x0 = tp[0];       x1 = tp[1]; }
    }
#pragma unroll
    for (int nt = 0; nt < 2; ++nt) {
      f32x4 v = acc[mt][nt];
      float own = sel4(v, rho);
      float r1  = __shfl_xor(sel4(v, rho ^ 1), 1, 64);
      float r2  = __shfl_xor(sel4(v, rho ^ 2), 2, 64);
      float r3  = __shfl_xor(sel4(v, rho ^ 3), 3, 64);
      float g0 = pick(rho,     own, r1, r2, r3);
      float g1 = pick(rho ^ 1, own, r1, r2, r3);
      float g2 = pick(rho ^ 2, own, r1, r2, r3);
      float g3 = pick(rho ^ 3, own, r1, r2, r3);
      if (act) {
        float4 bs = bsv[nt], w0 = w0v[nt], w1 = w1v[nt];
        float p0 = g0 + bs.x + w0.x * x0 + w1.x * x1;
        float p1 = g1 + bs.y + w0.y * x0 + w1.y * x1;
        float p2 = g2 + bs.z + w0.z * x0 + w1.z * x1;
        float p3 = g3 + bs.w + w0.w * x0 + w1.w * x1;
        int u = uu[nt];
        size_t ci = (size_t)row * 512 + u;
        float c_old = P.co[ci];
        float ii = sigm(p0), ff = sigm(p1), gg = tanh_f(p2), oo = sigm(p3);
        float cn = ff * c_old + ii * gg;
        float h  = oo * tanh_f(cn);
        P.co[ci] = cn;
        An[ci] = (__bf16)h;
        if (row == 4096) htn[u] = h;
      }
    }
  }
}

// ---------------------------------------------------------------------------
// Attention for step p, task b (64 tasks x 64 rows) + last-done finalize.
// ---------------------------------------------------------------------------
__device__ void do_att(const SP& P, int p, int b)
{
  __shared__ __align__(16) float qs[512];
  __shared__ float red[256];
  __shared__ float red2[256];
  __shared__ float es[64];
  __shared__ unsigned int sOld;
  const int t = threadIdx.x;
  const float* Z  = (p & 1) ? P.Z1 : P.Z0;
  const float* ht = P.ht + (size_t)p * 512;

  for (int c = t; c < 512; c += 256) qs[c] = Z[(size_t)4096 * NK + 1024 + c];
  __syncthreads();

  const int r0 = b * 64, rl = t >> 2, pp = t & 3;
  const float4* krow = (const float4*)(Z + (size_t)(r0 + rl) * NK);
  const float4* qs4  = (const float4*)qs;
  float a = 0.f;
  for (int i = pp; i < 128; i += 4) {
    float4 kk = krow[i], qq = qs4[i];
    a += kk.x * qq.x + kk.y * qq.y + kk.z * qq.z + kk.w * qq.w;
  }
  red[t] = a;
  __syncthreads();
  if (t < 64)
    es[t] = __expf((red[4 * t] + red[4 * t + 1] + red[4 * t + 2] + red[4 * t + 3]) *
                   0.04419417382415922f);
  __syncthreads();

  float s0 = 0.f, s1 = 0.f;
  for (int r = 0; r < 64; ++r) {
    const float* vr = Z + (size_t)(r0 + r) * NK + 512;
    float e = es[r];
    s0 += e * vr[t];
    s1 += e * vr[t + 256];
  }
  P.part[b * 513 + t] = s0;
  P.part[b * 513 + 256 + t] = s1;
  if (t == 0) {
    float se = 0.f;
#pragma unroll
    for (int r = 0; r < 64; ++r) se += es[r];
    P.part[b * 513 + 512] = se;
  }
  __threadfence();
  __syncthreads();
  if (t == 0) sOld = atomicAdd(P.cnt, 1u);
  __syncthreads();
  if (sOld == 63) {
    __threadfence();
    float s = 0.f, s2 = 0.f, se = 0.f;
    for (int bb = 0; bb < 64; ++bb) {
      s  += P.part[bb * 513 + t];
      s2 += P.part[bb * 513 + 256 + t];
      se += P.part[bb * 513 + 512];
    }
    float inv = 1.f / se;
    float va = ht[t] + s * inv + P.scene[t];
    float vb = ht[t + 256] + s2 * inv + P.scene[t + 256];
    red[t]  = va * P.out_w[t]       + vb * P.out_w[t + 256];
    red2[t] = va * P.out_w[512 + t] + vb * P.out_w[768 + t];
    __syncthreads();
    for (int st = 128; st > 0; st >>= 1) {
      if (t < st) { red[t] += red[t + st]; red2[t] += red2[t + st]; }
      __syncthreads();
    }
    if (t == 0) {
      P.out[2 * p]     = red[0]  + P.out_b[0];
      P.out[2 * p + 1] = red2[0] + P.out_b[1];
      *P.cnt = 0;
    }
  }
}

// ---------------------------------------------------------------------------
// Persistent cooperative main: 65 phases. Blocks 0..275: 2 gemm tiles.
// 276..447: 1 tile. 448..511: 1 tile + att(step p-1).
// ---------------------------------------------------------------------------
__global__ __launch_bounds__(256, 2) void sophie_main(SP P)
{
  cg::grid_group grid = cg::this_grid();
  const int blk = blockIdx.x;
  for (int p = 0; p <= 64; ++p) {
    if (p < 64) {
      do_gemm(P, p, blk);
      if (blk < 276) do_gemm(P, p, 512 + blk);
    }
    if (p >= 1 && blk >= 448) do_att(P, p - 1, blk - 448);
    grid.sync();
  }
}

// Fallback per-step kernels (same device functions, same numerics).
__global__ __launch_bounds__(256) void gemm_step(SP P, int p) {
  do_gemm(P, p, blockIdx.x);
}
__global__ __launch_bounds__(256) void att_step(SP P, int p) {
  do_att(P, p, blockIdx.x);
}

// ---------------------------------------------------------------------------
// Prep kernels (unchanged from R3, which passed).
// ---------------------------------------------------------------------------
__global__ __launch_bounds__(256) void init_state(
    const float* __restrict__ others0, const float* __restrict__ target0,
    const float* __restrict__ w_ih, const float* __restrict__ b_ih,
    const float* __restrict__ b_hh,
    float* __restrict__ co, __bf16* __restrict__ A0, float* __restrict__ ht0,
    unsigned int* __restrict__ cnt)
{
  int g = blockIdx.x * 256 + threadIdx.x;
  if (g == 0) *cnt = 0u;
  if (g >= 4097 * 512) return;
  int r = g >> 9, j = g & 511;
  float x0, x1;
  if (r < 4096) { x0 = others0[2 * r]; x1 = others0[2 * r + 1]; }
  else          { x0 = target0[0];     x1 = target0[1]; }
  float pre[4];
#pragma unroll
  for (int gg = 0; gg < 4; ++gg) {
    int n = gg * 512 + j;
    pre[gg] = b_ih[n] + b_hh[n] + w_ih[2 * n] * x0 + w_ih[2 * n + 1] * x1;
  }
  float cn = sigm(pre[0]) * tanh_f(pre[2]);
  float h  = sigm(pre[3]) * tanh_f(cn);
  co[g] = cn;
  A0[g] = (__bf16)h;
  if (r == 4096) ht0[j] = h;
}

__global__ __launch_bounds__(256) void pack_w(
    const float* __restrict__ w_hh, const float* __restrict__ wk,
    const float* __restrict__ wv,   const float* __restrict__ wq,
    __bf16* __restrict__ Wp)
{
  int o = blockIdx.x * 256 + threadIdx.x;
  int j = o & 7, nn = (o >> 3) & 15, kg = (o >> 7) & 63, ntg = o >> 13;
  int n = ntg * 16 + nn, k = kg * 8 + j;
  float v;
  if (n < 2048)      { int u = n >> 2, g = n & 3; v = w_hh[(g * 512 + u) * 512 + k]; }
  else if (n < 2560) v = wk[(n - 2048) * 512 + k];
  else if (n < 3072) v = wv[(n - 2560) * 512 + k];
  else               v = wq[(n - 3072) * 512 + k];
  Wp[o] = (__bf16)v;
}

__global__ __launch_bounds__(256) void pack_misc(
    const float* __restrict__ b_ih, const float* __restrict__ b_hh,
    const float* __restrict__ w_ih,
    const float* __restrict__ bk, const float* __restrict__ bv,
    const float* __restrict__ bq,
    float* __restrict__ bs, float* __restrict__ w0, float* __restrict__ w1,
    float* __restrict__ biasz)
{
  int i = blockIdx.x * 256 + threadIdx.x;
  if (i < 2048) {
    int u = i >> 2, g = i & 3, n = g * 512 + u;
    bs[i] = b_ih[n] + b_hh[n];
    w0[i] = w_ih[2 * n];
    w1[i] = w_ih[2 * n + 1];
  } else if (i < 2048 + 1536) {
    int z = i - 2048;
    biasz[z] = (z < 512) ? bk[z] : (z < 1024 ? bv[z - 512] : bq[z - 1024]);
  }
}

__global__ __launch_bounds__(256) void scene1_kernel(
    const int* __restrict__ map, const float* __restrict__ emb,
    const float* __restrict__ w1, const float* __restrict__ b1,
    float* __restrict__ out1)
{
  __shared__ float wl[576];
  __shared__ float bl[16];
  const int t = threadIdx.x;
  for (int i = t; i < 576; i += 256) wl[i] = w1[i];
  if (t < 16) bl[t] = b1[t];
  __syncthreads();
  const int y = blockIdx.x, x = t;
  float nb[4][9];
#pragma unroll
  for (int dy = 0; dy < 3; ++dy)
#pragma unroll
    for (int dx = 0; dx < 3; ++dx) {
      int yy = y + dy - 1, xx = x + dx - 1;
      bool ok = (yy >= 0 && yy < 256 && xx >= 0 && xx < 256);
      int m = ok ? map[yy * 256 + xx] : 0;
#pragma unroll
      for (int c = 0; c < 4; ++c)
        nb[c][dy * 3 + dx] = ok ? emb[m * 4 + c] : 0.f;
    }
  for (int oc = 0; oc < 16; ++oc) {
    float a = bl[oc];
#pragma unroll
    for (int c = 0; c < 4; ++c)
#pragma unroll
      for (int k = 0; k < 9; ++k) a += wl[(oc * 4 + c) * 9 + k] * nb[c][k];
    out1[oc * 65536 + y * 256 + x] = fmaxf(a, 0.f);
  }
}

__global__ __launch_bounds__(256) void scene2_kernel(
    const float* __restrict__ out1, const float* __restrict__ w2,
    const float* __restrict__ b2, float* __restrict__ rowpart)
{
  __shared__ float wl[1152];
  __shared__ float lds4[4 * 8];
  const int t = threadIdx.x;
  const int y = blockIdx.x & 255, ocg = blockIdx.x >> 8;
  for (int i = t; i < 1152; i += 256) wl[i] = w2[ocg * 1152 + i];
  __syncthreads();
  const int x = t;
  float acc[8];
#pragma unroll
  for (int o = 0; o < 8; ++o) acc[o] = b2[ocg * 8 + o];
  for (int ic = 0; ic < 16; ++ic) {
    float nb[9];
#pragma unroll
    for (int dy = 0; dy < 3; ++dy)
#pragma unroll
      for (int dx = 0; dx < 3; ++dx) {
        int yy = y + dy - 1, xx = x + dx - 1;
        bool ok = (yy >= 0 && yy < 256 && xx >= 0 && xx < 256);
        nb[dy * 3 + dx] = ok ? out1[ic * 65536 + yy * 256 + xx] : 0.f;
      }
#pragma unroll
    for (int o = 0; o < 8; ++o) {
      const float* w = &wl[(o * 16 + ic) * 9];
#pragma unroll
      for (int k = 0; k < 9; ++k) acc[o] += w[k] * nb[k];
    }
  }
  const int wave = t >> 6, lane = t & 63;
#pragma unroll
  for (int o = 0; o < 8; ++o) {
    float v = fmaxf(acc[o], 0.f);
#pragma unroll
    for (int m = 1; m < 64; m <<= 1) v += __shfl_xor(v, m, 64);
    if (lane == 0) lds4[wave * 8 + o] = v;
  }
  __syncthreads();
  if (t < 8)
    rowpart[y * 32 + ocg * 8 + t] = lds4[t] + lds4[8 + t] + lds4[16 + t] + lds4[24 + t];
}

__global__ __launch_bounds__(512) void scene3_kernel(
    const float* __restrict__ rowpart, const float* __restrict__ fcw,
    const float* __restrict__ fcb, float* __restrict__ scene)
{
  __shared__ float mean[32];
  const int t = threadIdx.x;
  if (t < 32) {
    float s = 0.f;
    for (int y = 0; y < 256; ++y) s += rowpart[y * 32 + t];
    mean[t] = s * (1.f / 65536.f);
  }
  __syncthreads();
  float a = fcb[t];
#pragma unroll
  for (int c = 0; c < 32; ++c) a += mean[c] * fcw[t * 32 + c];
  scene[t] = a;
}

// ---------------------------------------------------------------------------
extern "C" void kernel_launch(void* const* d_in, const int* in_sizes, int n_in,
                              void* d_out, int out_size, void* d_ws, size_t ws_size,
                              hipStream_t stream) {
  const float* target    = (const float*)d_in[0];
  const float* others    = (const float*)d_in[1];
  const int*   scene_map = (const int*)d_in[2];
  const float* emb       = (const float*)d_in[3];
  const float* c1w       = (const float*)d_in[4];
  const float* c1b       = (const float*)d_in[5];
  const float* c2w       = (const float*)d_in[6];
  const float* c2b       = (const float*)d_in[7];
  const float* fcw       = (const float*)d_in[8];
  const float* fcb       = (const float*)d_in[9];
  const float* w_ih      = (const float*)d_in[10];
  const float* w_hh      = (const float*)d_in[11];
  const float* b_ih      = (const float*)d_in[12];
  const float* b_hh      = (const float*)d_in[13];
  const float* wq        = (const float*)d_in[14];
  const float* bq        = (const float*)d_in[15];
  const float* wk        = (const float*)d_in[16];
  const float* bk        = (const float*)d_in[17];
  const float* wv        = (const float*)d_in[18];
  const float* bv        = (const float*)d_in[19];
  const float* out_w     = (const float*)d_in[20];
  const float* out_b     = (const float*)d_in[21];
  float* out = (float*)d_out;

  char* ws = (char*)d_ws;
  size_t off = 0;
  auto alloc = [&](size_t bytes) { size_t o = off; off += (bytes + 255) & ~(size_t)255; return o; };
  float*  Z0    = (float*)(ws + alloc((size_t)4224 * NK * 4));
  float*  Z1    = (float*)(ws + alloc((size_t)4224 * NK * 4));
  __bf16* Wp    = (__bf16*)(ws + alloc((size_t)1835008 * 2));
  __bf16* A0    = (__bf16*)(ws + alloc((size_t)4224 * 512 * 2));
  __bf16* A1    = (__bf16*)(ws + alloc((size_t)4224 * 512 * 2));
  float*  co    = (float*)(ws + alloc((size_t)4097 * 512 * 4));
  float*  ht    = (float*)(ws + alloc((size_t)65 * 512 * 4));
  float*  scene = (float*)(ws + alloc(2048));
  float*  part  = (float*)(ws + alloc(64 * 513 * 4));
  unsigned int* cnt = (unsigned int*)(ws + alloc(256));
  float*  bs    = (float*)(ws + alloc(2048 * 4));
  float*  w0p   = (float*)(ws + alloc(2048 * 4));
  float*  w1p   = (float*)(ws + alloc(2048 * 4));
  float*  biasz = (float*)(ws + alloc(1536 * 4));
  float*  out1  = (float*)(ws + alloc((size_t)16 * 65536 * 4));
  float*  rowp  = (float*)(ws + alloc(256 * 32 * 4));

  pack_w<<<7168, 256, 0, stream>>>(w_hh, wk, wv, wq, Wp);
  pack_misc<<<14, 256, 0, stream>>>(b_ih, b_hh, w_ih, bk, bv, bq, bs, w0p, w1p, biasz);
  scene1_kernel<<<256, 256, 0, stream>>>(scene_map, emb, c1w, c1b, out1);
  scene2_kernel<<<1024, 256, 0, stream>>>(out1, c2w, c2b, rowp);
  scene3_kernel<<<1, 512, 0, stream>>>(rowp, fcw, fcb, scene);
  init_state<<<8194, 256, 0, stream>>>(others, target, w_ih, b_ih, b_hh, co, A0, ht, cnt);

  SP hp;
  hp.Wp = (const unsigned short*)Wp;
  hp.A0 = (unsigned short*)A0; hp.A1 = (unsigned short*)A1;
  hp.Z0 = Z0; hp.Z1 = Z1;
  hp.co = co; hp.ht = ht;
  hp.biasz = biasz;
  hp.bs4 = (const float4*)bs; hp.w04 = (const float4*)w0p; hp.w14 = (const float4*)w1p;
  hp.others = others; hp.target = target;
  hp.scene = scene; hp.out_w = out_w; hp.out_b = out_b;
  hp.part = part; hp.cnt = cnt;
  hp.out = out;

  void* args[] = { (void*)&hp };
  hipError_t cerr = hipLaunchCooperativeKernel(
      reinterpret_cast<const void*>(&sophie_main), dim3(512), dim3(256),
      args, 0, stream);
  if (cerr != hipSuccess) {
    (void)hipGetLastError();   // clear sticky error, take fallback path
    for (int t = 0; t < 64; ++t) {
      gemm_step<<<788, 256, 0, stream>>>(hp, t);
      att_step<<<64, 256, 0, stream>>>(hp, t);
    }
  }
}

// Round 6
// 2950.540 us; speedup vs baseline: 3.2138x; 3.2138x over previous
//
#include <hip/hip_runtime.h>
#include <hip/hip_bf16.h>

// ---------------------------------------------------------------------------
// Sophie on MI355X, round 6: per-step dispatches (no coop), att(p-1) merged
// into gemm dispatch p as extra blocks. 128x256 tiles (14 bn strips -> half
// the A re-reads of R3), XCD-affine tile mapping (block%8 == bm%8) so A
// slices stay L2-resident per XCD.
// ---------------------------------------------------------------------------

typedef __bf16 bf16x8 __attribute__((ext_vector_type(8)));
typedef float  f32x4  __attribute__((ext_vector_type(4)));

#define NK 1536      // Z cols: k | v | q
#define KD 512

__device__ __forceinline__ void gl_lds16(const void* g, void* l) {
  __builtin_amdgcn_global_load_lds(
      (const __attribute__((address_space(1))) void*)g,
      (__attribute__((address_space(3))) void*)l, 16, 0, 0);
}
__device__ __forceinline__ float sigm(float x) {
  return __builtin_amdgcn_rcpf(1.f + __expf(-x));
}
__device__ __forceinline__ float tanh_f(float x) {
  return 2.f * __builtin_amdgcn_rcpf(1.f + __expf(-2.f * x)) - 1.f;
}
__device__ __forceinline__ float sel4(f32x4 v, int i) {
  float a = (i & 1) ? v[1] : v[0];
  float b = (i & 1) ? v[3] : v[2];
  return (i & 2) ? b : a;
}
__device__ __forceinline__ float pick(int m, float o0, float o1, float o2, float o3) {
  float a = (m & 1) ? o1 : o0;
  float b = (m & 1) ? o3 : o2;
  return (m & 2) ? b : a;
}

struct SP {
  const unsigned short* Wp;
  unsigned short* A0; unsigned short* A1;
  float* Z0; float* Z1;
  float* co; float* ht;            // ht[65][512]
  const float* biasz;
  const float4* bs4; const float4* w04; const float4* w14;
  const float* others; const float* target;
  const float* scene; const float* out_w; const float* out_b;
  float* part; unsigned int* cnt;
  float* out;
};

// ---------------------------------------------------------------------------
// One 128x256 GEMM tile for step p + fused epilogue.
// bn 0..7: gate cols (interleaved col=4u+g) -> LSTM epilogue.
// bn 8..13: k|v|q cols -> Z store with bias.
// A double-buffered in LDS (16KB/iter, global_load_lds 16B); B global->reg.
// Wave w owns cols [n0+64w, n0+64w+64) : 8 m-frags x 4 n-frags.
// ---------------------------------------------------------------------------
__device__ void do_gemm(const SP& P, int p, int bm, int bn)
{
  __shared__ __align__(16) char aLds[2][128 * 64 * 2];   // 32 KB

  const int tid = threadIdx.x, wave = tid >> 6, lane = tid & 63;
  const unsigned short* A = (p & 1) ? P.A1 : P.A0;
  __bf16* An = (__bf16*)((p & 1) ? P.A0 : P.A1);
  float* Z = (p & 1) ? P.Z1 : P.Z0;
  const int tin = (p + 1 < 31) ? (p + 1) : 31;
  const int tc  = (p + 1 < 63) ? (p + 1) : 63;
  const float* op = P.others + (size_t)tin * 8192;
  const float* tp = P.target + tc * 2;
  float* htn = P.ht + (size_t)(p + 1) * 512;

  const int m0 = bm * 128, n0 = bn * 256;
  const int l15 = lane & 15, lq = lane >> 4;

  int aRow[4], aOff[4], ldsOff[4];
#pragma unroll
  for (int j = 0; j < 4; ++j) {
    int chunk = j * 4 + wave;
    int r = chunk * 8 + (lane >> 3), ch = lane & 7;
    aRow[j]   = m0 + r;
    aOff[j]   = (ch ^ (r & 7)) * 8;
    ldsOff[j] = chunk * 1024;
  }
  // B: col group ntg = bn*16 + wave*4 + nt
  const unsigned short* bBase =
      P.Wp + (size_t)(bn * 16 + wave * 4) * 8192 + lq * 128 + l15 * 8;

  f32x4 acc[8][4];
#pragma unroll
  for (int i = 0; i < 8; ++i)
#pragma unroll
    for (int j = 0; j < 4; ++j) acc[i][j] = f32x4{0.f, 0.f, 0.f, 0.f};

#pragma unroll
  for (int j = 0; j < 4; ++j)
    gl_lds16(A + (size_t)aRow[j] * KD + aOff[j], aLds[0] + ldsOff[j]);
  __syncthreads();

  for (int it = 0; it < 8; ++it) {
    if (it < 7) {
      const int k1 = (it + 1) * 64;
#pragma unroll
      for (int j = 0; j < 4; ++j)
        gl_lds16(A + (size_t)aRow[j] * KD + k1 + aOff[j],
                 aLds[(it + 1) & 1] + ldsOff[j]);
    }
    const char* buf = aLds[it & 1];
#pragma unroll
    for (int c = 0; c < 2; ++c) {
      bf16x8 bC[4];
#pragma unroll
      for (int nt = 0; nt < 4; ++nt)
        bC[nt] = *(const bf16x8*)(bBase + nt * 8192 + it * 1024 + c * 512);
      bf16x8 af[8];
#pragma unroll
      for (int mt = 0; mt < 8; ++mt) {
        int row = mt * 16 + l15;
        int ch16 = (c * 4 + lq) ^ (row & 7);
        af[mt] = *(const bf16x8*)(buf + row * 128 + ch16 * 16);
      }
#pragma unroll
      for (int mt = 0; mt < 8; ++mt)
#pragma unroll
        for (int nt = 0; nt < 4; ++nt)
          acc[mt][nt] = __builtin_amdgcn_mfma_f32_16x16x32_bf16(
              af[mt], bC[nt], acc[mt][nt], 0, 0, 0);
    }
    __syncthreads();
  }

  const int rq = lq * 4;

  if (bn >= 8) {
    // ---- k/v/q epilogue: Z = acc + bias ----
    const int zb = n0 - 2048 + wave * 64;
    float bias[4];
#pragma unroll
    for (int nt = 0; nt < 4; ++nt) bias[nt] = P.biasz[zb + nt * 16 + l15];
#pragma unroll
    for (int mt = 0; mt < 8; ++mt) {
      int rowb = m0 + mt * 16 + rq;
#pragma unroll
      for (int nt = 0; nt < 4; ++nt) {
        int col = zb + nt * 16 + l15;
#pragma unroll
        for (int r = 0; r < 4; ++r)
          Z[(size_t)(rowb + r) * NK + col] = acc[mt][nt][r] + bias[nt];
      }
    }
    return;
  }

  // ---- gate epilogue: fused LSTM cell ----
  const int rho = lane & 3, usel = (lane >> 2) & 3;
  const int u0 = bn * 64 + wave * 16;
  float4 bsv[4], w0v[4], w1v[4];
  int uu[4];
#pragma unroll
  for (int nt = 0; nt < 4; ++nt) {
    uu[nt]  = u0 + nt * 4 + usel;
    bsv[nt] = P.bs4[uu[nt]];
    w0v[nt] = P.w04[uu[nt]];
    w1v[nt] = P.w14[uu[nt]];
  }
#pragma unroll
  for (int mt = 0; mt < 8; ++mt) {
    int row = m0 + mt * 16 + rq + rho;
    bool act = row <= 4096;
    float x0 = 0.f, x1 = 0.f;
    if (act) {
      if (row < 4096) { x0 = op[2 * row]; x1 = op[2 * row + 1]; }
      else            { x0 = tp[0];       x1 = tp[1]; }
    }
#pragma unroll
    for (int nt = 0; nt < 4; ++nt) {
      f32x4 v = acc[mt][nt];
      float own = sel4(v, rho);
      float r1  = __shfl_xor(sel4(v, rho ^ 1), 1, 64);
      float r2  = __shfl_xor(sel4(v, rho ^ 2), 2, 64);
      float r3  = __shfl_xor(sel4(v, rho ^ 3), 3, 64);
      float g0 = pick(rho,     own, r1, r2, r3);
      float g1 = pick(rho ^ 1, own, r1, r2, r3);
      float g2 = pick(rho ^ 2, own, r1, r2, r3);
      float g3 = pick(rho ^ 3, own, r1, r2, r3);
      if (act) {
        float4 bs = bsv[nt], w0 = w0v[nt], w1 = w1v[nt];
        float p0 = g0 + bs.x + w0.x * x0 + w1.x * x1;
        float p1 = g1 + bs.y + w0.y * x0 + w1.y * x1;
        float p2 = g2 + bs.z + w0.z * x0 + w1.z * x1;
        float p3 = g3 + bs.w + w0.w * x0 + w1.w * x1;
        int u = uu[nt];
        size_t ci = (size_t)row * 512 + u;
        float c_old = P.co[ci];
        float ii = sigm(p0), ff = sigm(p1), gg = tanh_f(p2), oo = sigm(p3);
        float cn = ff * c_old + ii * gg;
        float h  = oo * tanh_f(cn);
        P.co[ci] = cn;
        An[ci] = (__bf16)h;
        if (row == 4096) htn[u] = h;
      }
    }
  }
}

// ---------------------------------------------------------------------------
// Attention for step p, task b (64 tasks x 64 rows) + last-done finalize.
// (verified in R5)
// ---------------------------------------------------------------------------
__device__ void do_att(const SP& P, int p, int b)
{
  __shared__ __align__(16) float qs[512];
  __shared__ float red[256];
  __shared__ float red2[256];
  __shared__ float es[64];
  __shared__ unsigned int sOld;
  const int t = threadIdx.x;
  const float* Z  = (p & 1) ? P.Z1 : P.Z0;
  const float* ht = P.ht + (size_t)p * 512;

  for (int c = t; c < 512; c += 256) qs[c] = Z[(size_t)4096 * NK + 1024 + c];
  __syncthreads();

  const int r0 = b * 64, rl = t >> 2, pp = t & 3;
  const float4* krow = (const float4*)(Z + (size_t)(r0 + rl) * NK);
  const float4* qs4  = (const float4*)qs;
  float a = 0.f;
  for (int i = pp; i < 128; i += 4) {
    float4 kk = krow[i], qq = qs4[i];
    a += kk.x * qq.x + kk.y * qq.y + kk.z * qq.z + kk.w * qq.w;
  }
  red[t] = a;
  __syncthreads();
  if (t < 64)
    es[t] = __expf((red[4 * t] + red[4 * t + 1] + red[4 * t + 2] + red[4 * t + 3]) *
                   0.04419417382415922f);
  __syncthreads();

  float s0 = 0.f, s1 = 0.f;
  for (int r = 0; r < 64; ++r) {
    const float* vr = Z + (size_t)(r0 + r) * NK + 512;
    float e = es[r];
    s0 += e * vr[t];
    s1 += e * vr[t + 256];
  }
  P.part[b * 513 + t] = s0;
  P.part[b * 513 + 256 + t] = s1;
  if (t == 0) {
    float se = 0.f;
#pragma unroll
    for (int r = 0; r < 64; ++r) se += es[r];
    P.part[b * 513 + 512] = se;
  }
  __threadfence();
  __syncthreads();
  if (t == 0) sOld = atomicAdd(P.cnt, 1u);
  __syncthreads();
  if (sOld == 63) {
    __threadfence();
    float s = 0.f, s2 = 0.f, se = 0.f;
    for (int bb = 0; bb < 64; ++bb) {
      s  += P.part[bb * 513 + t];
      s2 += P.part[bb * 513 + 256 + t];
      se += P.part[bb * 513 + 512];
    }
    float inv = 1.f / se;
    float va = ht[t] + s * inv + P.scene[t];
    float vb = ht[t + 256] + s2 * inv + P.scene[t + 256];
    red[t]  = va * P.out_w[t]       + vb * P.out_w[t + 256];
    red2[t] = va * P.out_w[512 + t] + vb * P.out_w[768 + t];
    __syncthreads();
    for (int st = 128; st > 0; st >>= 1) {
      if (t < st) { red[t] += red[t + st]; red2[t] += red2[t + st]; }
      __syncthreads();
    }
    if (t == 0) {
      P.out[2 * p]     = red[0]  + P.out_b[0];
      P.out[2 * p + 1] = red2[0] + P.out_b[1];
      *P.cnt = 0;
    }
  }
}

// ---------------------------------------------------------------------------
// Step dispatch: 464 blocks. XCD-affine decode: x=b%8, s=b/8.
//  x==0, s in [48,58): bm=32 tiles (8 gate + 2 q).
//  s <48            : bm = x + 8*(s/12) (<32), ti=s%12 -> bn=ti (gates 0..7,
//                     kv 8..11).
//  x>0, s>=48       : att task a=(x-1)+7*(s-48) for step p-1 (a<64), else idle.
// ---------------------------------------------------------------------------
__global__ __launch_bounds__(256, 2) void step_kernel(SP P, int p)
{
  const int b = blockIdx.x, x = b & 7, s = b >> 3;
  if (x == 0 && s >= 48) {
    int ti = s - 48;                       // 0..9
    int bn = (ti < 8) ? ti : (12 + (ti - 8));
    do_gemm(P, p, 32, bn);
  } else if (s < 48) {
    int bm = x + 8 * (s / 12);
    int ti = s % 12;
    do_gemm(P, p, bm, ti);                 // bn = ti (0..11)
  } else {
    int a = (x - 1) + 7 * (s - 48);
    if (a < 64 && p >= 1) do_att(P, p - 1, a);
  }
}

__global__ __launch_bounds__(256) void att_step(SP P, int p) {
  do_att(P, p, blockIdx.x);
}

// ---------------------------------------------------------------------------
// Prep kernels (unchanged, verified).
// ---------------------------------------------------------------------------
__global__ __launch_bounds__(256) void init_state(
    const float* __restrict__ others0, const float* __restrict__ target0,
    const float* __restrict__ w_ih, const float* __restrict__ b_ih,
    const float* __restrict__ b_hh,
    float* __restrict__ co, __bf16* __restrict__ A0, float* __restrict__ ht0,
    unsigned int* __restrict__ cnt)
{
  int g = blockIdx.x * 256 + threadIdx.x;
  if (g == 0) *cnt = 0u;
  if (g >= 4097 * 512) return;
  int r = g >> 9, j = g & 511;
  float x0, x1;
  if (r < 4096) { x0 = others0[2 * r]; x1 = others0[2 * r + 1]; }
  else          { x0 = target0[0];     x1 = target0[1]; }
  float pre[4];
#pragma unroll
  for (int gg = 0; gg < 4; ++gg) {
    int n = gg * 512 + j;
    pre[gg] = b_ih[n] + b_hh[n] + w_ih[2 * n] * x0 + w_ih[2 * n + 1] * x1;
  }
  float cn = sigm(pre[0]) * tanh_f(pre[2]);
  float h  = sigm(pre[3]) * tanh_f(cn);
  co[g] = cn;
  A0[g] = (__bf16)h;
  if (r == 4096) ht0[j] = h;
}

__global__ __launch_bounds__(256) void pack_w(
    const float* __restrict__ w_hh, const float* __restrict__ wk,
    const float* __restrict__ wv,   const float* __restrict__ wq,
    __bf16* __restrict__ Wp)
{
  int o = blockIdx.x * 256 + threadIdx.x;
  int j = o & 7, nn = (o >> 3) & 15, kg = (o >> 7) & 63, ntg = o >> 13;
  int n = ntg * 16 + nn, k = kg * 8 + j;
  float v;
  if (n < 2048)      { int u = n >> 2, g = n & 3; v = w_hh[(g * 512 + u) * 512 + k]; }
  else if (n < 2560) v = wk[(n - 2048) * 512 + k];
  else if (n < 3072) v = wv[(n - 2560) * 512 + k];
  else               v = wq[(n - 3072) * 512 + k];
  Wp[o] = (__bf16)v;
}

__global__ __launch_bounds__(256) void pack_misc(
    const float* __restrict__ b_ih, const float* __restrict__ b_hh,
    const float* __restrict__ w_ih,
    const float* __restrict__ bk, const float* __restrict__ bv,
    const float* __restrict__ bq,
    float* __restrict__ bs, float* __restrict__ w0, float* __restrict__ w1,
    float* __restrict__ biasz)
{
  int i = blockIdx.x * 256 + threadIdx.x;
  if (i < 2048) {
    int u = i >> 2, g = i & 3, n = g * 512 + u;
    bs[i] = b_ih[n] + b_hh[n];
    w0[i] = w_ih[2 * n];
    w1[i] = w_ih[2 * n + 1];
  } else if (i < 2048 + 1536) {
    int z = i - 2048;
    biasz[z] = (z < 512) ? bk[z] : (z < 1024 ? bv[z - 512] : bq[z - 1024]);
  }
}

__global__ __launch_bounds__(256) void scene1_kernel(
    const int* __restrict__ map, const float* __restrict__ emb,
    const float* __restrict__ w1, const float* __restrict__ b1,
    float* __restrict__ out1)
{
  __shared__ float wl[576];
  __shared__ float bl[16];
  const int t = threadIdx.x;
  for (int i = t; i < 576; i += 256) wl[i] = w1[i];
  if (t < 16) bl[t] = b1[t];
  __syncthreads();
  const int y = blockIdx.x, x = t;
  float nb[4][9];
#pragma unroll
  for (int dy = 0; dy < 3; ++dy)
#pragma unroll
    for (int dx = 0; dx < 3; ++dx) {
      int yy = y + dy - 1, xx = x + dx - 1;
      bool ok = (yy >= 0 && yy < 256 && xx >= 0 && xx < 256);
      int m = ok ? map[yy * 256 + xx] : 0;
#pragma unroll
      for (int c = 0; c < 4; ++c)
        nb[c][dy * 3 + dx] = ok ? emb[m * 4 + c] : 0.f;
    }
  for (int oc = 0; oc < 16; ++oc) {
    float a = bl[oc];
#pragma unroll
    for (int c = 0; c < 4; ++c)
#pragma unroll
      for (int k = 0; k < 9; ++k) a += wl[(oc * 4 + c) * 9 + k] * nb[c][k];
    out1[oc * 65536 + y * 256 + x] = fmaxf(a, 0.f);
  }
}

__global__ __launch_bounds__(256) void scene2_kernel(
    const float* __restrict__ out1, const float* __restrict__ w2,
    const float* __restrict__ b2, float* __restrict__ rowpart)
{
  __shared__ float wl[1152];
  __shared__ float lds4[4 * 8];
  const int t = threadIdx.x;
  const int y = blockIdx.x & 255, ocg = blockIdx.x >> 8;
  for (int i = t; i < 1152; i += 256) wl[i] = w2[ocg * 1152 + i];
  __syncthreads();
  const int x = t;
  float acc[8];
#pragma unroll
  for (int o = 0; o < 8; ++o) acc[o] = b2[ocg * 8 + o];
  for (int ic = 0; ic < 16; ++ic) {
    float nb[9];
#pragma unroll
    for (int dy = 0; dy < 3; ++dy)
#pragma unroll
      for (int dx = 0; dx < 3; ++dx) {
        int yy = y + dy - 1, xx = x + dx - 1;
        bool ok = (yy >= 0 && yy < 256 && xx >= 0 && xx < 256);
        nb[dy * 3 + dx] = ok ? out1[ic * 65536 + yy * 256 + xx] : 0.f;
      }
#pragma unroll
    for (int o = 0; o < 8; ++o) {
      const float* w = &wl[(o * 16 + ic) * 9];
#pragma unroll
      for (int k = 0; k < 9; ++k) acc[o] += w[k] * nb[k];
    }
  }
  const int wave = t >> 6, lane = t & 63;
#pragma unroll
  for (int o = 0; o < 8; ++o) {
    float v = fmaxf(acc[o], 0.f);
#pragma unroll
    for (int m = 1; m < 64; m <<= 1) v += __shfl_xor(v, m, 64);
    if (lane == 0) lds4[wave * 8 + o] = v;
  }
  __syncthreads();
  if (t < 8)
    rowpart[y * 32 + ocg * 8 + t] = lds4[t] + lds4[8 + t] + lds4[16 + t] + lds4[24 + t];
}

__global__ __launch_bounds__(512) void scene3_kernel(
    const float* __restrict__ rowpart, const float* __restrict__ fcw,
    const float* __restrict__ fcb, float* __restrict__ scene)
{
  __shared__ float mean[32];
  const int t = threadIdx.x;
  if (t < 32) {
    float s = 0.f;
    for (int y = 0; y < 256; ++y) s += rowpart[y * 32 + t];
    mean[t] = s * (1.f / 65536.f);
  }
  __syncthreads();
  float a = fcb[t];
#pragma unroll
  for (int c = 0; c < 32; ++c) a += mean[c] * fcw[t * 32 + c];
  scene[t] = a;
}

// ---------------------------------------------------------------------------
extern "C" void kernel_launch(void* const* d_in, const int* in_sizes, int n_in,
                              void* d_out, int out_size, void* d_ws, size_t ws_size,
                              hipStream_t stream) {
  const float* target    = (const float*)d_in[0];
  const float* others    = (const float*)d_in[1];
  const int*   scene_map = (const int*)d_in[2];
  const float* emb       = (const float*)d_in[3];
  const float* c1w       = (const float*)d_in[4];
  const float* c1b       = (const float*)d_in[5];
  const float* c2w       = (const float*)d_in[6];
  const float* c2b       = (const float*)d_in[7];
  const float* fcw       = (const float*)d_in[8];
  const float* fcb       = (const float*)d_in[9];
  const float* w_ih      = (const float*)d_in[10];
  const float* w_hh      = (const float*)d_in[11];
  const float* b_ih      = (const float*)d_in[12];
  const float* b_hh      = (const float*)d_in[13];
  const float* wq        = (const float*)d_in[14];
  const float* bq        = (const float*)d_in[15];
  const float* wk        = (const float*)d_in[16];
  const float* bk        = (const float*)d_in[17];
  const float* wv        = (const float*)d_in[18];
  const float* bv        = (const float*)d_in[19];
  const float* out_w     = (const float*)d_in[20];
  const float* out_b     = (const float*)d_in[21];
  float* out = (float*)d_out;

  char* ws = (char*)d_ws;
  size_t off = 0;
  auto alloc = [&](size_t bytes) { size_t o = off; off += (bytes + 255) & ~(size_t)255; return o; };
  float*  Z0    = (float*)(ws + alloc((size_t)4224 * NK * 4));
  float*  Z1    = (float*)(ws + alloc((size_t)4224 * NK * 4));
  __bf16* Wp    = (__bf16*)(ws + alloc((size_t)1835008 * 2));
  __bf16* A0    = (__bf16*)(ws + alloc((size_t)4224 * 512 * 2));
  __bf16* A1    = (__bf16*)(ws + alloc((size_t)4224 * 512 * 2));
  float*  co    = (float*)(ws + alloc((size_t)4097 * 512 * 4));
  float*  ht    = (float*)(ws + alloc((size_t)65 * 512 * 4));
  float*  scene = (float*)(ws + alloc(2048));
  float*  part  = (float*)(ws + alloc(64 * 513 * 4));
  unsigned int* cnt = (unsigned int*)(ws + alloc(256));
  float*  bs    = (float*)(ws + alloc(2048 * 4));
  float*  w0p   = (float*)(ws + alloc(2048 * 4));
  float*  w1p   = (float*)(ws + alloc(2048 * 4));
  float*  biasz = (float*)(ws + alloc(1536 * 4));
  float*  out1  = (float*)(ws + alloc((size_t)16 * 65536 * 4));
  float*  rowp  = (float*)(ws + alloc(256 * 32 * 4));

  pack_w<<<7168, 256, 0, stream>>>(w_hh, wk, wv, wq, Wp);
  pack_misc<<<14, 256, 0, stream>>>(b_ih, b_hh, w_ih, bk, bv, bq, bs, w0p, w1p, biasz);
  scene1_kernel<<<256, 256, 0, stream>>>(scene_map, emb, c1w, c1b, out1);
  scene2_kernel<<<1024, 256, 0, stream>>>(out1, c2w, c2b, rowp);
  scene3_kernel<<<1, 512, 0, stream>>>(rowp, fcw, fcb, scene);
  init_state<<<8194, 256, 0, stream>>>(others, target, w_ih, b_ih, b_hh, co, A0, ht, cnt);

  SP hp;
  hp.Wp = (const unsigned short*)Wp;
  hp.A0 = (unsigned short*)A0; hp.A1 = (unsigned short*)A1;
  hp.Z0 = Z0; hp.Z1 = Z1;
  hp.co = co; hp.ht = ht;
  hp.biasz = biasz;
  hp.bs4 = (const float4*)bs; hp.w04 = (const float4*)w0p; hp.w14 = (const float4*)w1p;
  hp.others = others; hp.target = target;
  hp.scene = scene; hp.out_w = out_w; hp.out_b = out_b;
  hp.part = part; hp.cnt = cnt;
  hp.out = out;

  for (int p = 0; p < 64; ++p)
    step_kernel<<<464, 256, 0, stream>>>(hp, p);
  att_step<<<64, 256, 0, stream>>>(hp, 63);
}